// Round 1
// baseline (492.466 us; speedup 1.0000x reference)
//
#include <hip/hip_runtime.h>
#include <cstdint>
#include <cstddef>

// Problem constants
constexpr int T_N = 8192;   // rows of x / out
constexpr int MM  = 4096;   // K (cols of x, cols of W)
constexpr int NN  = 4096;   // rows of W / cols of out
constexpr int S_L = 2048;
constexpr int S_R = 2048;
constexpr float EPS_ = 1e-6f;

typedef float  f32x4  __attribute__((ext_vector_type(4)));
typedef __bf16 bf16x8 __attribute__((ext_vector_type(8)));
typedef unsigned short ushort8 __attribute__((ext_vector_type(8)));

__device__ __forceinline__ unsigned short f2bf(float f) {
  unsigned int u = __float_as_uint(f);
  u += 0x7FFFu + ((u >> 16) & 1u);   // round-to-nearest-even
  return (unsigned short)(u >> 16);
}

// ---------------------------------------------------------------------------
// Kernel 1: default maps (identity) — safety in case an index is unpaired
// ---------------------------------------------------------------------------
__global__ void init_maps(float* rowC, float* rowS, int* rowP,
                          float* colC, float* colS, int* colP) {
  int i = blockIdx.x * blockDim.x + threadIdx.x;
  if (i < NN) { rowC[i] = 1.f; rowS[i] = 0.f; rowP[i] = i; }
  if (i < MM) { colC[i] = 1.f; colS[i] = 0.f; colP[i] = i; }
}

// ---------------------------------------------------------------------------
// Kernel 2: per-index rotation maps from (pairs, theta).
// rotate: new[i] = c*old[i] - s*old[j];  new[j] = s*old[i] + c*old[j]
// => coef[idx]=c, cross[idx] = -s for first, +s for second, partner stored.
// ---------------------------------------------------------------------------
__global__ void build_maps(const float* __restrict__ thL, const float* __restrict__ thR,
                           const int* __restrict__ prL, const int* __restrict__ prR,
                           float* rowC, float* rowS, int* rowP,
                           float* colC, float* colS, int* colP) {
  int s = blockIdx.x * blockDim.x + threadIdx.x;
  if (s < S_L) {
    int i = prL[2*s], j = prL[2*s+1];
    float c = cosf(thL[s]), sn = sinf(thL[s]);
    rowC[i] = c; rowS[i] = -sn; rowP[i] = j;
    rowC[j] = c; rowS[j] =  sn; rowP[j] = i;
  }
  if (s < S_R) {
    int i = prR[2*s], j = prR[2*s+1];
    float c = cosf(thR[s]), sn = sinf(thR[s]);
    colC[i] = c; colS[i] = -sn; colP[i] = j;
    colC[j] = c; colS[j] =  sn; colP[j] = i;
  }
}

// ---------------------------------------------------------------------------
// Kernel 3: build W_eff row-by-row (one block per output row n):
//   V[r][m]     = cR[m]*W[r][m] + sR[m]*W[r][pR[m]]     (column rotation)
//   E[n][m]     = cL[n]*V[n][m] + sL[n]*V[pL[n]][m]     (row rotation)
//   scale       = base_row_norms[n]*exp(elm[n]) / sqrt(sum_m E^2 + EPS)
//   Wb[n][m]    = bf16(E[n][m]*scale)
// Rows n and pL[n] staged in LDS so the column gathers stay on-chip.
// ---------------------------------------------------------------------------
__global__ __launch_bounds__(256) void build_weff(
    const float* __restrict__ W, const float* __restrict__ brn, const float* __restrict__ elm,
    const float* __restrict__ rowC, const float* __restrict__ rowS, const int* __restrict__ rowP,
    const float* __restrict__ colC, const float* __restrict__ colS, const int* __restrict__ colP,
    unsigned short* __restrict__ Wb)
{
  __shared__ __align__(16) float rA[MM];
  __shared__ __align__(16) float rB[MM];
  __shared__ __align__(16) float rE[MM];
  __shared__ float red[4];

  int n   = blockIdx.x;
  int tid = threadIdx.x;
  int pn  = rowP[n];
  float cl = rowC[n], sl = rowS[n];
  const float* Wn = W + (size_t)n  * MM;
  const float* Wp = W + (size_t)pn * MM;

  for (int m = tid * 4; m < MM; m += 1024) {
    *(f32x4*)&rA[m] = *(const f32x4*)&Wn[m];
    *(f32x4*)&rB[m] = *(const f32x4*)&Wp[m];
  }
  __syncthreads();

  float ss = 0.f;
  for (int m = tid; m < MM; m += 256) {
    int p = colP[m];
    float c = colC[m], s = colS[m];
    float e = cl * (c * rA[m] + s * rA[p]) + sl * (c * rB[m] + s * rB[p]);
    rE[m] = e;
    ss += e * e;
  }
  #pragma unroll
  for (int o = 32; o; o >>= 1) ss += __shfl_xor(ss, o);
  int lane = tid & 63, wid = tid >> 6;
  if (lane == 0) red[wid] = ss;
  __syncthreads();
  float tot = red[0] + red[1] + red[2] + red[3];
  float scale = brn[n] * expf(elm[n]) / sqrtf(tot + EPS_);

  for (int m = tid * 8; m < MM; m += 2048) {
    ushort8 pkt;
    #pragma unroll
    for (int q = 0; q < 8; q++) pkt[q] = f2bf(rE[m + q] * scale);
    *(ushort8*)&Wb[(size_t)n * MM + m] = pkt;
  }
}

// ---------------------------------------------------------------------------
// Kernel 4: x (f32) -> bf16, vectorized 8 elems/thread/iter
// ---------------------------------------------------------------------------
__global__ __launch_bounds__(256) void conv_x(const float* __restrict__ x,
                                              unsigned short* __restrict__ xb) {
  const size_t total = (size_t)T_N * MM / 8;
  for (size_t i = (size_t)blockIdx.x * 256 + threadIdx.x; i < total; i += 2048ull * 256ull) {
    const float* s = x + i * 8;
    f32x4 v0 = *(const f32x4*)s;
    f32x4 v1 = *(const f32x4*)(s + 4);
    ushort8 p;
    p[0] = f2bf(v0.x); p[1] = f2bf(v0.y); p[2] = f2bf(v0.z); p[3] = f2bf(v0.w);
    p[4] = f2bf(v1.x); p[5] = f2bf(v1.y); p[6] = f2bf(v1.z); p[7] = f2bf(v1.w);
    *(ushort8*)(xb + i * 8) = p;
  }
}

// ---------------------------------------------------------------------------
// Kernel 5: GEMM  C[T][N] = A[T][M] * B[N][M]^T + bias   (bf16 MFMA, f32 out)
// m97 structure: 128x128 tile, BK=64, 4 waves (2x2, 64x64 out each),
// global_load_lds width-16 staging, 16x16x32 bf16 MFMA, 2 barriers/K-step.
// ---------------------------------------------------------------------------
constexpr int BM = 128, BN = 128, BK = 64;

typedef const __attribute__((address_space(1))) unsigned int* as1_u32p;
typedef __attribute__((address_space(3))) unsigned int* as3_u32p;

__device__ __forceinline__ void gl_lds16(const void* g, void* l) {
  __builtin_amdgcn_global_load_lds((as1_u32p)g, (as3_u32p)l, 16, 0, 0);
}

template <bool XB>
__global__ __launch_bounds__(256) void gemm_k(
    const unsigned short* __restrict__ xb, const float* __restrict__ xf,
    const unsigned short* __restrict__ wb, const float* __restrict__ bias,
    float* __restrict__ C)
{
  __shared__ __align__(16) unsigned short As[BM * BK];
  __shared__ __align__(16) unsigned short Bs[BN * BK];

  // XCD-aware swizzle: grid = 2048 = 64 (T tiles) x 32 (N tiles); 2048 % 8 == 0
  int bid = blockIdx.x;
  int swz = (bid & 7) * 256 + (bid >> 3);
  int tn = swz & 31;
  int tm = swz >> 5;

  int tid  = threadIdx.x;
  int lane = tid & 63;
  int wid  = tid >> 6;
  int wr = wid >> 1, wc = wid & 1;  // wave coords in 2x2
  int lr = lane & 15;               // fragment row/col index
  int lg = lane >> 4;               // k-group (8 bf16 each)

  f32x4 acc[4][4];
  #pragma unroll
  for (int i = 0; i < 4; i++)
    #pragma unroll
    for (int j = 0; j < 4; j++) {
      f32x4 z = {0.f, 0.f, 0.f, 0.f};
      acc[i][j] = z;
    }

  int srow = tid >> 3;            // 0..31 (row within 32-row chunk)
  int scol = (tid & 7) * 8;       // element col within BK
  const size_t a_base = (size_t)(tm * BM) * MM;
  const size_t b_base = (size_t)(tn * BN) * MM;

  for (int k0 = 0; k0 < MM; k0 += BK) {
    // ---- stage B tile (always bf16 via global_load_lds) ----
    #pragma unroll
    for (int c = 0; c < 4; c++) {
      int row = c * 32 + srow;
      gl_lds16(wb + b_base + (size_t)row * MM + k0 + scol,
               (char*)Bs + (c * 256 + wid * 64) * 16);
    }
    // ---- stage A tile ----
    if (XB) {
      #pragma unroll
      for (int c = 0; c < 4; c++) {
        int row = c * 32 + srow;
        gl_lds16(xb + a_base + (size_t)row * MM + k0 + scol,
                 (char*)As + (c * 256 + wid * 64) * 16);
      }
    } else {
      #pragma unroll
      for (int c = 0; c < 4; c++) {
        int row = c * 32 + srow;
        const float* s = xf + a_base + (size_t)row * MM + k0 + scol;
        f32x4 v0 = *(const f32x4*)s;
        f32x4 v1 = *(const f32x4*)(s + 4);
        ushort8 p;
        p[0] = f2bf(v0.x); p[1] = f2bf(v0.y); p[2] = f2bf(v0.z); p[3] = f2bf(v0.w);
        p[4] = f2bf(v1.x); p[5] = f2bf(v1.y); p[6] = f2bf(v1.z); p[7] = f2bf(v1.w);
        *(ushort8*)&As[(c * 256 + tid) * 8] = p;
      }
    }
    __syncthreads();

    // ---- compute: 2 k-slices of 32, 4x4 fragments of 16x16 per wave ----
    #pragma unroll
    for (int kk = 0; kk < 2; kk++) {
      bf16x8 a[4], b[4];
      #pragma unroll
      for (int i = 0; i < 4; i++) {
        a[i] = *(const bf16x8*)&As[(wr * 64 + i * 16 + lr) * BK + kk * 32 + lg * 8];
        b[i] = *(const bf16x8*)&Bs[(wc * 64 + i * 16 + lr) * BK + kk * 32 + lg * 8];
      }
      #pragma unroll
      for (int i = 0; i < 4; i++)
        #pragma unroll
        for (int j = 0; j < 4; j++)
          acc[i][j] = __builtin_amdgcn_mfma_f32_16x16x32_bf16(a[i], b[j], acc[i][j], 0, 0, 0);
    }
    __syncthreads();
  }

  // ---- epilogue: C/D layout col = lane&15, row = (lane>>4)*4 + reg ----
  int gn0 = tn * BN + wc * 64;
  int gt0 = tm * BM + wr * 64;
  #pragma unroll
  for (int j = 0; j < 4; j++) {
    int gn = gn0 + j * 16 + lr;
    float bi = bias[gn];
    #pragma unroll
    for (int i = 0; i < 4; i++) {
      int t0 = gt0 + i * 16 + lg * 4;
      #pragma unroll
      for (int q = 0; q < 4; q++)
        C[(size_t)(t0 + q) * NN + gn] = acc[i][j][q] + bi;
    }
  }
}

// ---------------------------------------------------------------------------
extern "C" void kernel_launch(void* const* d_in, const int* in_sizes, int n_in,
                              void* d_out, int out_size, void* d_ws, size_t ws_size,
                              hipStream_t stream)
{
  const float* x    = (const float*)d_in[0];
  const float* W    = (const float*)d_in[1];
  const float* bias = (const float*)d_in[2];
  const float* thL  = (const float*)d_in[3];
  const float* thR  = (const float*)d_in[4];
  const float* elm  = (const float*)d_in[5];
  const float* brn  = (const float*)d_in[6];
  const int*   prL  = (const int*)d_in[7];
  const int*   prR  = (const int*)d_in[8];
  float* out = (float*)d_out;

  char* ws = (char*)d_ws;
  unsigned short* Wb = (unsigned short*)ws;          // N*M bf16 = 33.5 MB
  size_t off = (size_t)NN * MM * 2;
  float* rowC = (float*)(ws + off); off += NN * 4;
  float* rowS = (float*)(ws + off); off += NN * 4;
  int*   rowP = (int*)  (ws + off); off += NN * 4;
  float* colC = (float*)(ws + off); off += MM * 4;
  float* colS = (float*)(ws + off); off += MM * 4;
  int*   colP = (int*)  (ws + off); off += MM * 4;
  unsigned short* xb = (unsigned short*)(ws + off);  // T*M bf16 = 67 MB (optional)
  bool use_xb = ws_size >= off + (size_t)T_N * MM * 2;

  init_maps <<<16, 256, 0, stream>>>(rowC, rowS, rowP, colC, colS, colP);
  build_maps<<< 8, 256, 0, stream>>>(thL, thR, prL, prR, rowC, rowS, rowP, colC, colS, colP);
  build_weff<<<NN, 256, 0, stream>>>(W, brn, elm, rowC, rowS, rowP, colC, colS, colP, Wb);

  if (use_xb) {
    conv_x<<<2048, 256, 0, stream>>>(x, xb);
    gemm_k<true><<<2048, 256, 0, stream>>>(xb, x, Wb, bias, out);
  } else {
    gemm_k<false><<<2048, 256, 0, stream>>>(xb, x, Wb, bias, out);
  }
}

// Round 2
// 382.805 us; speedup vs baseline: 1.2865x; 1.2865x over previous
//
#include <hip/hip_runtime.h>
#include <cstdint>
#include <cstddef>

// Problem constants
constexpr int T_N = 8192;   // rows of x / out
constexpr int MM  = 4096;   // K (cols of x, cols of W)
constexpr int NN  = 4096;   // rows of W / cols of out
constexpr int S_L = 2048;
constexpr int S_R = 2048;
constexpr float EPS_ = 1e-6f;

typedef float  f32x4  __attribute__((ext_vector_type(4)));
typedef __bf16 bf16x8 __attribute__((ext_vector_type(8)));
typedef unsigned short ushort8 __attribute__((ext_vector_type(8)));

__device__ __forceinline__ unsigned short f2bf(float f) {
  unsigned int u = __float_as_uint(f);
  u += 0x7FFFu + ((u >> 16) & 1u);   // round-to-nearest-even
  return (unsigned short)(u >> 16);
}

// ---------------------------------------------------------------------------
// Kernel 1: default maps (identity)
// ---------------------------------------------------------------------------
__global__ void init_maps(float* rowC, float* rowS, int* rowP,
                          float* colC, float* colS, int* colP) {
  int i = blockIdx.x * blockDim.x + threadIdx.x;
  if (i < NN) { rowC[i] = 1.f; rowS[i] = 0.f; rowP[i] = i; }
  if (i < MM) { colC[i] = 1.f; colS[i] = 0.f; colP[i] = i; }
}

// ---------------------------------------------------------------------------
// Kernel 2: per-index rotation maps from (pairs, theta).
// ---------------------------------------------------------------------------
__global__ void build_maps(const float* __restrict__ thL, const float* __restrict__ thR,
                           const int* __restrict__ prL, const int* __restrict__ prR,
                           float* rowC, float* rowS, int* rowP,
                           float* colC, float* colS, int* colP) {
  int s = blockIdx.x * blockDim.x + threadIdx.x;
  if (s < S_L) {
    int i = prL[2*s], j = prL[2*s+1];
    float c = cosf(thL[s]), sn = sinf(thL[s]);
    rowC[i] = c; rowS[i] = -sn; rowP[i] = j;
    rowC[j] = c; rowS[j] =  sn; rowP[j] = i;
  }
  if (s < S_R) {
    int i = prR[2*s], j = prR[2*s+1];
    float c = cosf(thR[s]), sn = sinf(thR[s]);
    colC[i] = c; colS[i] = -sn; colP[i] = j;
    colC[j] = c; colS[j] =  sn; colP[j] = i;
  }
}

// ---------------------------------------------------------------------------
// Kernel 3: build W_eff row-by-row, fused row-norm, emit bf16.
// ---------------------------------------------------------------------------
__global__ __launch_bounds__(256) void build_weff(
    const float* __restrict__ W, const float* __restrict__ brn, const float* __restrict__ elm,
    const float* __restrict__ rowC, const float* __restrict__ rowS, const int* __restrict__ rowP,
    const float* __restrict__ colC, const float* __restrict__ colS, const int* __restrict__ colP,
    unsigned short* __restrict__ Wb)
{
  __shared__ __align__(16) float rA[MM];
  __shared__ __align__(16) float rB[MM];
  __shared__ __align__(16) float rE[MM];
  __shared__ float red[4];

  int n   = blockIdx.x;
  int tid = threadIdx.x;
  int pn  = rowP[n];
  float cl = rowC[n], sl = rowS[n];
  const float* Wn = W + (size_t)n  * MM;
  const float* Wp = W + (size_t)pn * MM;

  for (int m = tid * 4; m < MM; m += 1024) {
    *(f32x4*)&rA[m] = *(const f32x4*)&Wn[m];
    *(f32x4*)&rB[m] = *(const f32x4*)&Wp[m];
  }
  __syncthreads();

  float ss = 0.f;
  for (int m = tid; m < MM; m += 256) {
    int p = colP[m];
    float c = colC[m], s = colS[m];
    float e = cl * (c * rA[m] + s * rA[p]) + sl * (c * rB[m] + s * rB[p]);
    rE[m] = e;
    ss += e * e;
  }
  #pragma unroll
  for (int o = 32; o; o >>= 1) ss += __shfl_xor(ss, o);
  int lane = tid & 63, wid = tid >> 6;
  if (lane == 0) red[wid] = ss;
  __syncthreads();
  float tot = red[0] + red[1] + red[2] + red[3];
  float scale = brn[n] * expf(elm[n]) / sqrtf(tot + EPS_);

  for (int m = tid * 8; m < MM; m += 2048) {
    ushort8 pkt;
    #pragma unroll
    for (int q = 0; q < 8; q++) pkt[q] = f2bf(rE[m + q] * scale);
    *(ushort8*)&Wb[(size_t)n * MM + m] = pkt;
  }
}

// ---------------------------------------------------------------------------
// Kernel 4: x (f32) -> bf16
// ---------------------------------------------------------------------------
__global__ __launch_bounds__(256) void conv_x(const float* __restrict__ x,
                                              unsigned short* __restrict__ xb) {
  const size_t total = (size_t)T_N * MM / 8;
  for (size_t i = (size_t)blockIdx.x * 256 + threadIdx.x; i < total; i += 2048ull * 256ull) {
    const float* s = x + i * 8;
    f32x4 v0 = *(const f32x4*)s;
    f32x4 v1 = *(const f32x4*)(s + 4);
    ushort8 p;
    p[0] = f2bf(v0.x); p[1] = f2bf(v0.y); p[2] = f2bf(v0.z); p[3] = f2bf(v0.w);
    p[4] = f2bf(v1.x); p[5] = f2bf(v1.y); p[6] = f2bf(v1.z); p[7] = f2bf(v1.w);
    *(ushort8*)(xb + i * 8) = p;
  }
}

// ---------------------------------------------------------------------------
// global->LDS async staging helper (16B, linear LDS dest)
// ---------------------------------------------------------------------------
typedef const __attribute__((address_space(1))) unsigned int* as1_u32p;
typedef __attribute__((address_space(3))) unsigned int* as3_u32p;

__device__ __forceinline__ void gl_lds16(const void* g, void* l) {
  __builtin_amdgcn_global_load_lds((as1_u32p)g, (as3_u32p)l, 16, 0, 0);
}

// ---------------------------------------------------------------------------
// Kernel 5a: 256x256 8-phase GEMM  C[T][N] = A[T][M] * B[N][M]^T + bias
//   bf16 MFMA 16x16x32, 8 waves (2Mx4N), per-wave 128x64, acc[8][4].
//   LDS 128 KiB: double-buffered 256x64 bf16 tiles for A and B.
//   T2: XOR-swizzle byte^=((row&7)<<4), applied on ds_read AND pre-applied
//       to the global source address (LDS dest stays linear for gl_lds).
//   T3/T4: 4 phases per K-tile; next tile's 8 gl_lds issued at phase 0;
//       per-wave vmcnt(0) at phase 3 before boundary barrier.
//   T5: setprio(1) around each 16-MFMA cluster.
// ---------------------------------------------------------------------------
constexpr int GBM = 256, GBN = 256, GBK = 64;
constexpr int NT_K = MM / GBK;   // 64

__global__ __launch_bounds__(512, 2) void gemm8(
    const unsigned short* __restrict__ xb,
    const unsigned short* __restrict__ wb,
    const float* __restrict__ bias,
    float* __restrict__ C)
{
  __shared__ __align__(16) unsigned short As[2][GBM * GBK];  // 64 KiB
  __shared__ __align__(16) unsigned short Bs[2][GBN * GBK];  // 64 KiB

  // grid = 512 = 32 (tm) x 16 (tn); 512 % 8 == 0 -> simple XCD swizzle
  int bid = blockIdx.x;
  int swz = (bid & 7) * 64 + (bid >> 3);
  int tn = swz & 15, tm = swz >> 4;
  const int trow0 = tm * GBM;
  const int tcol0 = tn * GBN;

  int tid  = threadIdx.x;
  int lane = tid & 63;
  int wid  = tid >> 6;
  int wr = wid >> 2, wc = wid & 3;   // wave coords: 2 x 4
  int lr = lane & 15;                // fragment row/col
  int lg = lane >> 4;                // k-group
  int sw = (lr & 7) << 4;            // T2 read-side swizzle term (byte)

  f32x4 acc[8][4];
  #pragma unroll
  for (int i = 0; i < 8; i++)
    #pragma unroll
    for (int j = 0; j < 4; j++) {
      f32x4 z = {0.f, 0.f, 0.f, 0.f};
      acc[i][j] = z;
    }

  // stage one 256x64 K-tile of operand g (row-major, ld=MM) into lds[buf].
  // LDS dest linear; source column-group XORed by (row&7) => after linear
  // write, LDS holds the swizzled layout the ds_reads expect.
  auto stage = [&](const unsigned short* g, int grow0, int k0,
                   unsigned short (*lds)[GBM * GBK], int buf) {
    #pragma unroll
    for (int l = 0; l < 4; ++l) {
      int off16 = l * 512 + tid;         // 16B unit index, 0..2047
      int row   = off16 >> 3;            // 0..255
      int colu  = off16 & 7;             // 16B slot within 128B row
      const unsigned short* src =
          g + (size_t)(grow0 + row) * MM + k0 + ((colu ^ (row & 7)) << 3);
      gl_lds16(src, (char*)lds[buf] + off16 * 16);
    }
  };

  // prologue: stage tile 0 into buffer 0, drain, sync
  stage(xb, trow0, 0, As, 0);
  stage(wb, tcol0, 0, Bs, 0);
  asm volatile("s_waitcnt vmcnt(0)" ::: "memory");
  __builtin_amdgcn_s_barrier();

  bf16x8 bfr[4][2];
  for (int t = 0; t < NT_K; ++t) {
    int cur = t & 1;
    const char* Ab = (const char*)As[cur];
    const char* Bb = (const char*)Bs[cur];
    #pragma unroll
    for (int q = 0; q < 4; ++q) {
      // ---- ds_reads for this phase (swizzled addresses) ----
      if (q == 0) {
        #pragma unroll
        for (int ni = 0; ni < 4; ++ni)
          #pragma unroll
          for (int kk = 0; kk < 2; ++kk)
            bfr[ni][kk] = *(const bf16x8*)(Bb + (wc * 64 + ni * 16 + lr) * 128
                                              + ((kk * 64 + lg * 16) ^ sw));
      }
      bf16x8 af[2][2];
      #pragma unroll
      for (int i = 0; i < 2; ++i)
        #pragma unroll
        for (int kk = 0; kk < 2; ++kk)
          af[i][kk] = *(const bf16x8*)(Ab + (wr * 128 + (q * 2 + i) * 16 + lr) * 128
                                          + ((kk * 64 + lg * 16) ^ sw));
      // ---- issue next K-tile staging (phase 0 only: max latency cover) ----
      if (q == 0 && t + 1 < NT_K) {
        stage(xb, trow0, (t + 1) * GBK, As, cur ^ 1);
        stage(wb, tcol0, (t + 1) * GBK, Bs, cur ^ 1);
      }
      __builtin_amdgcn_s_barrier();
      asm volatile("s_waitcnt lgkmcnt(0)" ::: "memory");
      __builtin_amdgcn_sched_barrier(0);
      __builtin_amdgcn_s_setprio(1);
      #pragma unroll
      for (int kk = 0; kk < 2; ++kk)
        #pragma unroll
        for (int i = 0; i < 2; ++i)
          #pragma unroll
          for (int ni = 0; ni < 4; ++ni)
            acc[q * 2 + i][ni] = __builtin_amdgcn_mfma_f32_16x16x32_bf16(
                af[i][kk], bfr[ni][kk], acc[q * 2 + i][ni], 0, 0, 0);
      __builtin_amdgcn_s_setprio(0);
      if (q == 3) asm volatile("s_waitcnt vmcnt(0)" ::: "memory");
      __builtin_amdgcn_s_barrier();
    }
  }

  // ---- epilogue: C/D layout col = lane&15, row = (lane>>4)*4 + reg ----
  #pragma unroll
  for (int ni = 0; ni < 4; ++ni) {
    int col = tcol0 + wc * 64 + ni * 16 + lr;
    float bi = bias[col];
    #pragma unroll
    for (int mi = 0; mi < 8; ++mi) {
      int r0 = trow0 + wr * 128 + mi * 16 + lg * 4;
      #pragma unroll
      for (int qq = 0; qq < 4; ++qq)
        C[(size_t)(r0 + qq) * NN + col] = acc[mi][ni][qq] + bi;
    }
  }
}

// ---------------------------------------------------------------------------
// Kernel 5b (fallback, ws too small for xb): m97-style 128x128 GEMM with
// inline f32->bf16 A-staging. (Round-1 verified path.)
// ---------------------------------------------------------------------------
constexpr int BM = 128, BN = 128, BK = 64;

__global__ __launch_bounds__(256) void gemm_fb(
    const float* __restrict__ xf,
    const unsigned short* __restrict__ wb, const float* __restrict__ bias,
    float* __restrict__ C)
{
  __shared__ __align__(16) unsigned short As[BM * BK];
  __shared__ __align__(16) unsigned short Bs[BN * BK];

  int bid = blockIdx.x;
  int swz = (bid & 7) * 256 + (bid >> 3);
  int tn = swz & 31;
  int tm = swz >> 5;

  int tid  = threadIdx.x;
  int lane = tid & 63;
  int wid  = tid >> 6;
  int wr = wid >> 1, wc = wid & 1;
  int lr = lane & 15;
  int lg = lane >> 4;

  f32x4 acc[4][4];
  #pragma unroll
  for (int i = 0; i < 4; i++)
    #pragma unroll
    for (int j = 0; j < 4; j++) {
      f32x4 z = {0.f, 0.f, 0.f, 0.f};
      acc[i][j] = z;
    }

  int srow = tid >> 3;
  int scol = (tid & 7) * 8;
  const size_t a_base = (size_t)(tm * BM) * MM;
  const size_t b_base = (size_t)(tn * BN) * MM;

  for (int k0 = 0; k0 < MM; k0 += BK) {
    #pragma unroll
    for (int c = 0; c < 4; c++) {
      int row = c * 32 + srow;
      gl_lds16(wb + b_base + (size_t)row * MM + k0 + scol,
               (char*)Bs + (c * 256 + wid * 64) * 16);
    }
    #pragma unroll
    for (int c = 0; c < 4; c++) {
      int row = c * 32 + srow;
      const float* s = xf + a_base + (size_t)row * MM + k0 + scol;
      f32x4 v0 = *(const f32x4*)s;
      f32x4 v1 = *(const f32x4*)(s + 4);
      ushort8 p;
      p[0] = f2bf(v0.x); p[1] = f2bf(v0.y); p[2] = f2bf(v0.z); p[3] = f2bf(v0.w);
      p[4] = f2bf(v1.x); p[5] = f2bf(v1.y); p[6] = f2bf(v1.z); p[7] = f2bf(v1.w);
      *(ushort8*)&As[(c * 256 + tid) * 8] = p;
    }
    __syncthreads();

    #pragma unroll
    for (int kk = 0; kk < 2; kk++) {
      bf16x8 a[4], b[4];
      #pragma unroll
      for (int i = 0; i < 4; i++) {
        a[i] = *(const bf16x8*)&As[(wr * 64 + i * 16 + lr) * BK + kk * 32 + lg * 8];
        b[i] = *(const bf16x8*)&Bs[(wc * 64 + i * 16 + lr) * BK + kk * 32 + lg * 8];
      }
      #pragma unroll
      for (int i = 0; i < 4; i++)
        #pragma unroll
        for (int j = 0; j < 4; j++)
          acc[i][j] = __builtin_amdgcn_mfma_f32_16x16x32_bf16(a[i], b[j], acc[i][j], 0, 0, 0);
    }
    __syncthreads();
  }

  int gn0 = tn * BN + wc * 64;
  int gt0 = tm * BM + wr * 64;
  #pragma unroll
  for (int j = 0; j < 4; j++) {
    int gn = gn0 + j * 16 + lr;
    float bi = bias[gn];
    #pragma unroll
    for (int i = 0; i < 4; i++) {
      int t0 = gt0 + i * 16 + lg * 4;
      #pragma unroll
      for (int q = 0; q < 4; q++)
        C[(size_t)(t0 + q) * NN + gn] = acc[i][j][q] + bi;
    }
  }
}

// ---------------------------------------------------------------------------
extern "C" void kernel_launch(void* const* d_in, const int* in_sizes, int n_in,
                              void* d_out, int out_size, void* d_ws, size_t ws_size,
                              hipStream_t stream)
{
  const float* x    = (const float*)d_in[0];
  const float* W    = (const float*)d_in[1];
  const float* bias = (const float*)d_in[2];
  const float* thL  = (const float*)d_in[3];
  const float* thR  = (const float*)d_in[4];
  const float* elm  = (const float*)d_in[5];
  const float* brn  = (const float*)d_in[6];
  const int*   prL  = (const int*)d_in[7];
  const int*   prR  = (const int*)d_in[8];
  float* out = (float*)d_out;

  char* ws = (char*)d_ws;
  unsigned short* Wb = (unsigned short*)ws;          // N*M bf16 = 33.5 MB
  size_t off = (size_t)NN * MM * 2;
  float* rowC = (float*)(ws + off); off += NN * 4;
  float* rowS = (float*)(ws + off); off += NN * 4;
  int*   rowP = (int*)  (ws + off); off += NN * 4;
  float* colC = (float*)(ws + off); off += MM * 4;
  float* colS = (float*)(ws + off); off += MM * 4;
  int*   colP = (int*)  (ws + off); off += MM * 4;
  unsigned short* xb = (unsigned short*)(ws + off);  // T*M bf16 = 67 MB
  bool use_xb = ws_size >= off + (size_t)T_N * MM * 2;

  init_maps <<<16, 256, 0, stream>>>(rowC, rowS, rowP, colC, colS, colP);
  build_maps<<< 8, 256, 0, stream>>>(thL, thR, prL, prR, rowC, rowS, rowP, colC, colS, colP);
  build_weff<<<NN, 256, 0, stream>>>(W, brn, elm, rowC, rowS, rowP, colC, colS, colP, Wb);

  if (use_xb) {
    conv_x<<<2048, 256, 0, stream>>>(x, xb);
    gemm8<<<512, 512, 0, stream>>>(xb, Wb, bias, out);
  } else {
    gemm_fb<<<2048, 256, 0, stream>>>(x, Wb, bias, out);
  }
}